// Round 10
// baseline (495.102 us; speedup 1.0000x reference)
//
#include <hip/hip_runtime.h>
#include <math.h>

// Problem constants (match reference)
#define BB 4
#define CC 256
#define HH 128
#define WW 128
#define MM 8
#define PP 4
#define DD 32
#define LQ 16384  // HH*WW

typedef float f4v __attribute__((ext_vector_type(4)));
typedef float f2v __attribute__((ext_vector_type(2)));

// ---------------------------------------------------------------------------
// K1 (occupancy rework): value[b][lq][c] = sum_ci collab[b][ci][lq]*Wv[ci][c]+bv
// R9 evidence: 40KB-LDS / 4 blocks/CU / acc[8][8] version ran ~200us (~3.6x
// VALU ideal) -- same TLP-starvation pattern as K2/K3. This version: tile
// 32 lq x 256 c, 16-ci chunks, LDS 18 KB (sw_[16][256]+sc[16][32]),
// acc[4][8]=32 regs -> ~6-8 waves/SIMD; grid 2048 = 8 blocks/CU (two
// generations -> staging overlaps compute, no lockstep).
// LDS reads: W = 32 lanes x contiguous float4 (conflict-free, K2-verified
// pattern); collab = 2-address b128 broadcast (free).
// ---------------------------------------------------------------------------
__global__ __launch_bounds__(256) void k_value(
    const float* __restrict__ collab, const float* __restrict__ Wv,
    const float* __restrict__ bv, float* __restrict__ value)
{
  __shared__ float sw_[16][256];  // 16 KB
  __shared__ float sc[16][32];    //  2 KB
  const int b   = blockIdx.y;
  const int lq0 = blockIdx.x * 32;
  const int t   = threadIdx.x;

  const int c_lo = (t & 31) * 4;  // cols {c_lo..+3} and {c_lo+128..+3}
  const int l0   = (t >> 5) * 4;  // 4 lq rows

  float acc[4][8];
  #pragma unroll
  for (int i = 0; i < 4; ++i)
    #pragma unroll
    for (int j = 0; j < 8; ++j) acc[i][j] = 0.f;

  const int wrb  = (t >> 6) * 4;  // W stage: rows wrb..wrb+3
  const int wc4  = (t & 63) * 4;  // W stage: col (64 thr x 16B = 1KB row)
  const int crow = t >> 4;        // collab stage: row 0..15
  const int ccol = (t & 15) * 2;  // collab stage: col (float2)

  for (int ch = 0; ch < 16; ++ch) {
    __syncthreads();
    // Stage W chunk: 16 rows x 256 cols, coalesced float4.
    #pragma unroll
    for (int i = 0; i < 4; ++i) {
      const int r = wrb + i;
      *(f4v*)(&sw_[r][wc4]) =
          *(const f4v*)(Wv + (size_t)(ch * 16 + r) * CC + wc4);
    }
    // Stage collab chunk: 16 rows x 32 lq, coalesced float2 (8B/lane).
    *(f2v*)(&sc[crow][ccol]) =
        *(const f2v*)(collab + ((size_t)(b * CC + ch * 16 + crow)) * LQ + lq0 + ccol);
    __syncthreads();

    #pragma unroll 4
    for (int ci = 0; ci < 16; ++ci) {
      const f4v a  = *(const f4v*)(&sc[ci][l0]);
      const f4v w0 = *(const f4v*)(&sw_[ci][c_lo]);
      const f4v w1 = *(const f4v*)(&sw_[ci][c_lo + 128]);
      #pragma unroll
      for (int i = 0; i < 4; ++i) {
        const float ai = a[i];
        #pragma unroll
        for (int j = 0; j < 4; ++j) {
          acc[i][j]     = fmaf(ai, w0[j], acc[i][j]);
          acc[i][4 + j] = fmaf(ai, w1[j], acc[i][4 + j]);
        }
      }
    }
  }

  const f4v bv0 = *(const f4v*)(bv + c_lo);
  const f4v bv1 = *(const f4v*)(bv + c_lo + 128);
  #pragma unroll
  for (int i = 0; i < 4; ++i) {
    f4v o0, o1;
    #pragma unroll
    for (int j = 0; j < 4; ++j) {
      o0[j] = acc[i][j] + bv0[j];
      o1[j] = acc[i][4 + j] + bv1[j];
    }
    float* dst = value + ((size_t)(b * LQ) + lq0 + l0 + i) * CC + c_lo;
    *(f4v*)dst         = o0;
    *(f4v*)(dst + 128) = o1;
  }
}

// ---------------------------------------------------------------------------
// K2 (grid rework): [Lq,256] @ [256, 64+32] per batch. R9 evidence: 128-lq
// tile -> grid 512 = only 2 blocks/CU (grid-limited TLP). Now 64-lq tile ->
// grid 1024 = 4 blocks/CU; LDS 20 KB (sa[32][64]+so[32][64]+swa[32][32]);
// thread = 2 lq x one head (24 accs). W reads broadcast (free); q read =
// f2v at 8B stride -> 2-way alias = free.
// Epilogue: softmax over P + SCRAMBLED coords (reference's (2,P)->(P,2)
// reshape; exact with H==W==128):
//   p'=0: (w+o0, w+o2)  p'=1: (w+o4, w+o6)  p'=2: (h+o1, h+o3)  p'=3: (h+o5, h+o7)
// Stores la[b][lq][m][p'][3] = {gx_pix, gy_pix, attn_w} as 3 float4s/head.
// ---------------------------------------------------------------------------
__global__ __launch_bounds__(256) void k_offattn(
    const float* __restrict__ ego, const float* __restrict__ Wo,
    const float* __restrict__ bo, const float* __restrict__ Wa,
    const float* __restrict__ ba, float* __restrict__ la)
{
  __shared__ float sa[32][64];   //  8 KB
  __shared__ float so[32][64];   //  8 KB
  __shared__ float swa[32][32];  //  4 KB
  const int b    = blockIdx.y;
  const int lq0  = blockIdx.x * 64;
  const int t    = threadIdx.x;
  const int lsub = t & 31;  // lq = lq0 + lsub*2 + i
  const int m    = t >> 5;  // head 0..7 (uniform per 32-lane half-wave)

  float ao[2][8];
  float aa[2][4];
  #pragma unroll
  for (int i = 0; i < 2; ++i) {
    #pragma unroll
    for (int j = 0; j < 8; ++j) ao[i][j] = 0.f;
    #pragma unroll
    for (int p = 0; p < 4; ++p) aa[i][p] = 0.f;
  }

  for (int chunk = 0; chunk < 8; ++chunk) {
    __syncthreads();
    // Stage ego chunk: rows chunk*32+r, 64 lq wide.
    {
      const int r0 = t >> 4;        // 0..15
      const int c4 = (t & 15) * 4;  // 0..60
      #pragma unroll
      for (int it = 0; it < 2; ++it) {
        const int r = it * 16 + r0;
        *(f4v*)(&sa[r][c4]) =
            *(const f4v*)(ego + ((size_t)(b * CC) + chunk * 32 + r) * LQ + lq0 + c4);
      }
    }
    // Stage W_off chunk: 32 rows x 64.
    {
      const int r0 = t >> 4;        // 0..15
      const int c4 = (t & 15) * 4;  // 0..60
      #pragma unroll
      for (int it = 0; it < 2; ++it) {
        const int r = it * 16 + r0;
        *(f4v*)(&so[r][c4]) = *(const f4v*)(Wo + (size_t)(chunk * 32 + r) * 64 + c4);
      }
    }
    // Stage W_attn chunk: 32 rows x 32.
    {
      const int r  = t >> 3;       // 0..31
      const int c4 = (t & 7) * 4;  // 0..28
      *(f4v*)(&swa[r][c4]) = *(const f4v*)(Wa + (size_t)(chunk * 32 + r) * 32 + c4);
    }
    __syncthreads();

    #pragma unroll 4
    for (int ci = 0; ci < 32; ++ci) {
      const f2v q   = *(const f2v*)(&sa[ci][lsub * 2]);
      const f4v wo0 = *(const f4v*)(&so[ci][m * 8]);
      const f4v wo1 = *(const f4v*)(&so[ci][m * 8 + 4]);
      const f4v wa4 = *(const f4v*)(&swa[ci][m * 4]);
      #pragma unroll
      for (int i = 0; i < 2; ++i) {
        const float qq = q[i];
        #pragma unroll
        for (int j = 0; j < 4; ++j) {
          ao[i][j]     = fmaf(qq, wo0[j], ao[i][j]);
          ao[i][4 + j] = fmaf(qq, wo1[j], ao[i][4 + j]);
          aa[i][j]     = fmaf(qq, wa4[j], aa[i][j]);
        }
      }
    }
  }

  // Epilogue: bias + softmax + coord scramble + store (per head m, 2 lqs).
  const f4v bo0 = *(const f4v*)(bo + m * 8);
  const f4v bo1 = *(const f4v*)(bo + m * 8 + 4);
  const f4v ba0 = *(const f4v*)(ba + m * 4);

  #pragma unroll
  for (int i = 0; i < 2; ++i) {
    const int lq = lq0 + lsub * 2 + i;
    const int h  = lq >> 7;
    const int w  = lq & (WW - 1);
    const float fw = (float)w, fh = (float)h;

    float lg[4];
    #pragma unroll
    for (int p = 0; p < 4; ++p) lg[p] = aa[i][p] + ba0[p];
    const float mx = fmaxf(fmaxf(lg[0], lg[1]), fmaxf(lg[2], lg[3]));
    float e[4];
    float s = 0.f;
    #pragma unroll
    for (int p = 0; p < 4; ++p) { e[p] = expf(lg[p] - mx); s += e[p]; }
    const float inv = 1.0f / s;

    float o[8];
    #pragma unroll
    for (int j = 0; j < 4; ++j) { o[j] = ao[i][j] + bo0[j]; o[4 + j] = ao[i][4 + j] + bo1[j]; }

    const float gx[4] = {fw + o[0], fw + o[4], fh + o[1], fh + o[5]};
    const float gy[4] = {fw + o[2], fw + o[6], fh + o[3], fh + o[7]};
    const float aw[4] = {e[0] * inv, e[1] * inv, e[2] * inv, e[3] * inv};
    float4 s0, s1, s2;
    s0.x = gx[0]; s0.y = gy[0]; s0.z = aw[0]; s0.w = gx[1];
    s1.x = gy[1]; s1.y = aw[1]; s1.z = gx[2]; s1.w = gy[2];
    s2.x = aw[2]; s2.y = gx[3]; s2.z = gy[3]; s2.w = aw[3];
    float* mp = la + ((size_t)(b * LQ) + lq) * (MM * PP * 3) + m * 12;
    *(float4*)(mp + 0) = s0;
    *(float4*)(mp + 4) = s1;
    *(float4*)(mp + 8) = s2;
  }
}

// ---------------------------------------------------------------------------
// K3 (fused sample + output GEMM + residual).  BYTE-IDENTICAL anchor
// (196-198 us, VALUBusy 51%, bank conflicts 0 in R7/R9).
// ---------------------------------------------------------------------------
__global__ __launch_bounds__(256) void k_sample_out(
    const float* __restrict__ value, const float* __restrict__ la,
    const float* __restrict__ Wt, const float* __restrict__ bt,
    const float* __restrict__ ego, float* __restrict__ out)
{
  __shared__ float tmp[32][256];  // 32 KB
  const int b   = blockIdx.y;
  const int lq0 = blockIdx.x * 32;
  const int t   = threadIdx.x;

  // ---- Phase B: bilinear sampling ----
  {
    const int sub = t & 7;
    const int m   = (t >> 3) & 7;
    const int wv  = t >> 6;  // wave id 0..3
    const int cc  = m * 32 + sub * 4;
    const float* vb = value + (size_t)b * LQ * CC + cc;

    #pragma unroll
    for (int it = 0; it < 8; ++it) {
      const int ll = it * 4 + wv;  // 0..31
      const float* pla = la + (((size_t)(b * LQ) + lq0 + ll) * MM + m) * (PP * 3);
      const float4 q0 = *(const float4*)(pla + 0);
      const float4 q1 = *(const float4*)(pla + 4);
      const float4 q2 = *(const float4*)(pla + 8);
      const float gxa[4] = {q0.x, q0.w, q1.z, q2.y};
      const float gya[4] = {q0.y, q1.x, q1.w, q2.z};
      const float awa[4] = {q0.z, q1.y, q2.x, q2.w};

      float a0 = 0.f, a1 = 0.f, a2 = 0.f, a3 = 0.f;

      #pragma unroll
      for (int pp2 = 0; pp2 < 2; ++pp2) {
        int   offs[2][4];
        float wts[2][4];
        #pragma unroll
        for (int pi = 0; pi < 2; ++pi) {
          const int p = pp2 * 2 + pi;
          const float gx = gxa[p], gy = gya[p], aw = awa[p];
          const float fx0 = floorf(gx), fy0 = floorf(gy);
          const float wx1 = gx - fx0, wy1 = gy - fy0;
          const float vxl = (fx0 >= 0.f && fx0 <= 127.f) ? 1.f : 0.f;
          const float vxr = (fx0 >= -1.f && fx0 <= 126.f) ? 1.f : 0.f;
          const float vyt = (fy0 >= 0.f && fy0 <= 127.f) ? 1.f : 0.f;
          const float vyb = (fy0 >= -1.f && fy0 <= 126.f) ? 1.f : 0.f;
          const int ixl = (int)fminf(fmaxf(fx0, 0.f), 127.f);
          const int ixr = (int)fminf(fmaxf(fx0 + 1.f, 0.f), 127.f);
          const int iyt = (int)fminf(fmaxf(fy0, 0.f), 127.f);
          const int iyb = (int)fminf(fmaxf(fy0 + 1.f, 0.f), 127.f);
          const float wxl = (1.f - wx1) * vxl, wxr = wx1 * vxr;
          const float wyt = (1.f - wy1) * vyt, wyb = wy1 * vyb;
          const int rT = iyt * WW, rB = iyb * WW;
          offs[pi][0] = (rT + ixl) * CC; wts[pi][0] = aw * wxl * wyt;
          offs[pi][1] = (rT + ixr) * CC; wts[pi][1] = aw * wxr * wyt;
          offs[pi][2] = (rB + ixl) * CC; wts[pi][2] = aw * wxl * wyb;
          offs[pi][3] = (rB + ixr) * CC; wts[pi][3] = aw * wxr * wyb;
        }
        f4v vv[2][4];
        #pragma unroll
        for (int pi = 0; pi < 2; ++pi)
          #pragma unroll
          for (int c = 0; c < 4; ++c)
            vv[pi][c] = *(const f4v*)(vb + offs[pi][c]);
        #pragma unroll
        for (int pi = 0; pi < 2; ++pi)
          #pragma unroll
          for (int c = 0; c < 4; ++c) {
            const float wc = wts[pi][c];
            a0 = fmaf(wc, vv[pi][c][0], a0);
            a1 = fmaf(wc, vv[pi][c][1], a1);
            a2 = fmaf(wc, vv[pi][c][2], a2);
            a3 = fmaf(wc, vv[pi][c][3], a3);
          }
      }

      const int c_sw = cc ^ ((ll & 7) << 2);
      f4v wr; wr[0] = a0; wr[1] = a1; wr[2] = a2; wr[3] = a3;
      *(f4v*)(&tmp[ll][c_sw]) = wr;
    }
  }
  __syncthreads();

  // ---- Phase C: out-projection GEMM + bias + residual ----
  const int lr  = t & 7;
  const int co0 = (t >> 3) * 8;
  const int sw  = lr << 2;

  float acc[4][8];
  #pragma unroll
  for (int i = 0; i < 4; ++i)
    #pragma unroll
    for (int j = 0; j < 8; ++j) acc[i][j] = 0.f;

  for (int ci0 = 0; ci0 < CC; ci0 += 4) {
    f4v pa[4];
    #pragma unroll
    for (int i = 0; i < 4; ++i)
      pa[i] = *(const f4v*)(&tmp[lr + 8 * i][ci0 ^ sw]);
    f4v wv4[4][2];
    #pragma unroll
    for (int j = 0; j < 4; ++j) {
      wv4[j][0] = *(const f4v*)(Wt + (size_t)(ci0 + j) * CC + co0);
      wv4[j][1] = *(const f4v*)(Wt + (size_t)(ci0 + j) * CC + co0 + 4);
    }
    #pragma unroll
    for (int i = 0; i < 4; ++i)
      #pragma unroll
      for (int j = 0; j < 4; ++j) {
        const float a = pa[i][j];
        #pragma unroll
        for (int k = 0; k < 4; ++k) {
          acc[i][k]     = fmaf(a, wv4[j][0][k], acc[i][k]);
          acc[i][4 + k] = fmaf(a, wv4[j][1][k], acc[i][4 + k]);
        }
      }
  }

  const f4v bt0 = *(const f4v*)(bt + co0);
  const f4v bt1 = *(const f4v*)(bt + co0 + 4);
  #pragma unroll
  for (int i = 0; i < 4; ++i) {
    const int lq = lq0 + lr + 8 * i;
    #pragma unroll
    for (int j = 0; j < 8; ++j) {
      const int co = co0 + j;
      const size_t idx = ((size_t)(b * CC) + co) * LQ + lq;
      const float bias = (j < 4) ? bt0[j & 3] : bt1[j & 3];
      out[idx] = acc[i][j] + bias + ego[idx];
    }
  }
}

// ---------------------------------------------------------------------------
extern "C" void kernel_launch(void* const* d_in, const int* in_sizes, int n_in,
                              void* d_out, int out_size, void* d_ws, size_t ws_size,
                              hipStream_t stream) {
  (void)in_sizes; (void)n_in; (void)out_size; (void)ws_size;
  const float* ego    = (const float*)d_in[0];
  const float* collab = (const float*)d_in[1];
  const float* W_off  = (const float*)d_in[2];
  const float* b_off  = (const float*)d_in[3];
  const float* W_attn = (const float*)d_in[4];
  const float* b_attn = (const float*)d_in[5];
  const float* W_val  = (const float*)d_in[6];
  const float* b_val  = (const float*)d_in[7];
  const float* W_out  = (const float*)d_in[8];
  const float* b_out  = (const float*)d_in[9];
  float* out = (float*)d_out;

  // Workspace: value [B][Lq][C] (67.1 MB) then la [B][Lq][M][P][3] (25.2 MB)
  float* value = (float*)d_ws;
  float* la    = value + (size_t)BB * LQ * CC;

  k_value<<<dim3(LQ / 32, BB), 256, 0, stream>>>(collab, W_val, b_val, value);
  k_offattn<<<dim3(LQ / 64, BB), 256, 0, stream>>>(ego, W_off, b_off, W_attn, b_attn, la);
  k_sample_out<<<dim3(LQ / 32, BB), 256, 0, stream>>>(value, la, W_out, b_out, ego, out);
}